// Round 6
// baseline (99.814 us; speedup 1.0000x reference)
//
#include <hip/hip_runtime.h>
#include <math.h>

#define NN   8192
#define K    1024          // buckets over T in [0,1): avg occupancy 8
#define NT   1024          // threads (16 waves, one block, one CU)
#define EPT  8             // elements per thread
#define EPSF 1e-6f

// O(N) algorithm exploiting T ~ uniform[0,1):
//   bucket b(t) = floor(t*K) is monotone => cross-bucket order is exact;
//   sum_r[i] = exclusive-suffix-of-bucket-ER-sums[b] + strict walk in bucket
//   sum_s[i] = exclusive-prefix-of-bucket-ES-sums[b] + strict walk in bucket
// Everything in ONE block => one launch, no cross-block coherence, in-block
// final reduction. LDS: 96 KB sorted arrays + 20 KB bucket arrays = 116 KB.

__device__ __forceinline__ float wave_incl_scan_f(float x, int lane) {
#pragma unroll
  for (int off = 1; off < 64; off <<= 1) {
    float y = __shfl_up(x, off);
    if (lane >= off) x += y;
  }
  return x;
}
__device__ __forceinline__ unsigned wave_incl_scan_u(unsigned x, int lane) {
#pragma unroll
  for (int off = 1; off < 64; off <<= 1) {
    unsigned y = __shfl_up(x, off);
    if (lane >= off) x += y;
  }
  return x;
}

// Block-wide exclusive scan (NT=1024 -> 16 waves). Uniform control flow;
// caller must __syncthreads() before reusing wtmp.
__device__ __forceinline__ float block_excl_scan_f(float v, float* wtmp, int tid) {
  const int lane = tid & 63, wid = tid >> 6;
  float incl = wave_incl_scan_f(v, lane);
  if (lane == 63) wtmp[wid] = incl;
  __syncthreads();
  if (tid < 64) {
    float w = (tid < 16) ? wtmp[tid] : 0.0f;
    w = wave_incl_scan_f(w, lane);
    if (tid < 16) wtmp[tid] = w;
  }
  __syncthreads();
  float base = (wid > 0) ? wtmp[wid - 1] : 0.0f;
  return base + incl - v;
}
__device__ __forceinline__ unsigned block_excl_scan_u(unsigned v, unsigned* wtmp, int tid) {
  const int lane = tid & 63, wid = tid >> 6;
  unsigned incl = wave_incl_scan_u(v, lane);
  if (lane == 63) wtmp[wid] = incl;
  __syncthreads();
  if (tid < 64) {
    unsigned w = (tid < 16) ? wtmp[tid] : 0u;
    w = wave_incl_scan_u(w, lane);
    if (tid < 16) wtmp[tid] = w;
  }
  __syncthreads();
  unsigned base = (wid > 0) ? wtmp[wid - 1] : 0u;
  return base + incl - v;
}

__global__ __launch_bounds__(NT) void ds_all(
    const float* __restrict__ Pr, const float* __restrict__ Ps,
    const float* __restrict__ T,  const int* __restrict__ E,
    float* __restrict__ out) {
  __shared__ unsigned cnt[K];    // histogram -> exclusive start offsets
  __shared__ unsigned cur[K];    // scatter cursors
  __shared__ float    bER[K];    // bucket ER sums -> exclusive SUFFIX sums
  __shared__ float    bES[K];    // bucket ES sums -> exclusive PREFIX sums
  __shared__ float    sT[NN];    // counting-sorted (by bucket) T
  __shared__ float    sER[NN];
  __shared__ float    sES[NN];
  __shared__ float    wtmp[64];  // scan / final-reduce scratch

  const int tid  = threadIdx.x;
  const int lane = tid & 63, wid = tid >> 6;

  cnt[tid] = 0u; cur[tid] = 0u; bER[tid] = 0.0f; bES[tid] = 0.0f;
  __syncthreads();

  // ---- Phase A: vectorized load of 8 contiguous elems/thread + histogram
  float t8[EPT], pr8[EPT], ps8[EPT], er8[EPT], es8[EPT];
  int   ev8[EPT], b8[EPT];
  {
    const int j = tid * EPT;
    float4 ta = *(const float4*)(T  + j), tb = *(const float4*)(T  + j + 4);
    float4 pa = *(const float4*)(Pr + j), pb = *(const float4*)(Pr + j + 4);
    float4 qa = *(const float4*)(Ps + j), qb = *(const float4*)(Ps + j + 4);
    int4   ea = *(const int4*)(E + j),    eb = *(const int4*)(E + j + 4);
    t8[0]=ta.x;  t8[1]=ta.y;  t8[2]=ta.z;  t8[3]=ta.w;
    t8[4]=tb.x;  t8[5]=tb.y;  t8[6]=tb.z;  t8[7]=tb.w;
    pr8[0]=pa.x; pr8[1]=pa.y; pr8[2]=pa.z; pr8[3]=pa.w;
    pr8[4]=pb.x; pr8[5]=pb.y; pr8[6]=pb.z; pr8[7]=pb.w;
    ps8[0]=qa.x; ps8[1]=qa.y; ps8[2]=qa.z; ps8[3]=qa.w;
    ps8[4]=qb.x; ps8[5]=qb.y; ps8[6]=qb.z; ps8[7]=qb.w;
    ev8[0]=ea.x; ev8[1]=ea.y; ev8[2]=ea.z; ev8[3]=ea.w;
    ev8[4]=eb.x; ev8[5]=eb.y; ev8[6]=eb.z; ev8[7]=eb.w;
  }
#pragma unroll
  for (int e = 0; e < EPT; ++e) {
    er8[e] = __expf(pr8[e]);
    es8[e] = ev8[e] ? __expf(ps8[e]) : 0.0f;
    int b = (int)(t8[e] * (float)K);
    b = min(max(b, 0), K - 1);
    b8[e] = b;
    atomicAdd(&cnt[b], 1u);
    atomicAdd(&bER[b], er8[e]);
    atomicAdd(&bES[b], es8[e]);
  }
  __syncthreads();

  // ---- Phase B: three block scans (counts->starts, ES prefix, ER suffix)
  unsigned myc  = cnt[tid];
  float    myes = bES[tid];
  float    myerR = bER[K - 1 - tid];       // reversed read => suffix scan
  __syncthreads();
  unsigned startv = block_excl_scan_u(myc, (unsigned*)wtmp, tid);
  __syncthreads();
  float prees = block_excl_scan_f(myes, wtmp, tid);
  __syncthreads();
  float sufR = block_excl_scan_f(myerR, wtmp, tid);
  __syncthreads();
  cnt[tid] = startv;                        // cnt now = exclusive start
  bES[tid] = prees;                         // bES now = exclusive prefix
  bER[K - 1 - tid] = sufR;                  // bER now = exclusive suffix
  __syncthreads();

  // ---- Phase C: counting-sort scatter into LDS
#pragma unroll
  for (int e = 0; e < EPT; ++e) {
    unsigned pos = cnt[b8[e]] + atomicAdd(&cur[b8[e]], 1u);
    sT[pos]  = t8[e];
    sER[pos] = er8[e];
    sES[pos] = es8[e];
  }
  __syncthreads();

  // ---- Phase D: per element, bucket base + strict in-bucket walk
  float nr = 0.0f, dr = 0.0f, ns = 0.0f, nds = 0.0f;
#pragma unroll
  for (int e = 0; e < EPT; ++e) {
    const int   b = b8[e];
    const float t = t8[e];
    float srv = bER[b];                           // buckets strictly above
    float ssv = bES[b];                           // buckets strictly below
    const unsigned p0 = cnt[b];
    const unsigned p1 = (b == K - 1) ? (unsigned)NN : cnt[b + 1];
    for (unsigned p = p0; p < p1; ++p) {          // avg 8 members; self excluded
      float tj = sT[p];                           //   by strict compares
      srv += (tj > t) ? sER[p] : 0.0f;
      ssv += (tj < t) ? sES[p] : 0.0f;
    }
    const float wr  = (ev8[e] != 0 && srv > 0.0f) ? 1.0f : 0.0f;
    const float wsv = (ssv > 0.0f) ? 1.0f : 0.0f;
    nr  += wr  * (pr8[e] - logf(srv + EPSF));
    dr  += wr;
    ns  += wsv * (ps8[e] - logf(ssv + EPSF));
    nds += wsv;
  }

  // ---- Phase E: block reduction of the 4 loss accumulators
#pragma unroll
  for (int off = 32; off > 0; off >>= 1) {
    nr  += __shfl_down(nr,  off);
    dr  += __shfl_down(dr,  off);
    ns  += __shfl_down(ns,  off);
    nds += __shfl_down(nds, off);
  }
  if (lane == 0) {
    wtmp[wid] = nr; wtmp[16 + wid] = dr; wtmp[32 + wid] = ns; wtmp[48 + wid] = nds;
  }
  __syncthreads();
  if (tid == 0) {
    float NR = 0, DR = 0, NS = 0, DS = 0;
#pragma unroll
    for (int w = 0; w < 16; ++w) {
      NR += wtmp[w]; DR += wtmp[16 + w]; NS += wtmp[32 + w]; DS += wtmp[48 + w];
    }
    out[0] = -NR / DR;
    out[1] = -NS / DS;
  }
}

extern "C" void kernel_launch(void* const* d_in, const int* in_sizes, int n_in,
                              void* d_out, int out_size, void* d_ws, size_t ws_size,
                              hipStream_t stream) {
  const float* Pr = (const float*)d_in[0];
  const float* Ps = (const float*)d_in[1];
  const float* T  = (const float*)d_in[2];
  const int*   E  = (const int*)d_in[3];
  float* out = (float*)d_out;

  ds_all<<<1, NT, 0, stream>>>(Pr, Ps, T, E, out);   // single launch, O(N)
}

// Round 7
// 75.956 us; speedup vs baseline: 1.3141x; 1.3141x over previous
//
#include <hip/hip_runtime.h>
#include <math.h>

#define NN   8192
#define R    8              // rows per block
#define HALF (NN / 2)       // j-range split in two -> 2x blocks -> 8 waves/SIMD
#define GX   ((NN / R) * 2) // 2048 blocks = 8 blocks/CU = 32 waves/CU

#define EPSF 1e-6f

// ws layout: sumR0[NN], sumR1[NN], sumS0[NN], sumS1[NN]  (128 KB total).
// Block (g,h) writes rows [g*8, g*8+8) of half h -> every slot written every
// call (no init needed despite 0xAA poison). No atomics, no fences: cross-
// kernel visibility via the kernel boundary (R3/R5-proven).

__global__ __launch_bounds__(256, 8) void ds_main(
    const float* __restrict__ Pr, const float* __restrict__ Ps,
    const float* __restrict__ T,  const int* __restrict__ E,
    float* __restrict__ sumR0, float* __restrict__ sumR1,
    float* __restrict__ sumS0, float* __restrict__ sumS1) {
  const int tid   = threadIdx.x;
  const int g     = blockIdx.x >> 1;        // row group
  const int h     = blockIdx.x & 1;         // j half
  const int row0  = g * R;
  const int jbase = h * HALF;

  float Ti[R];
#pragma unroll
  for (int r = 0; r < R; ++r) Ti[r] = T[row0 + r];   // block-uniform -> s_load

  float sr[R], ss[R];
#pragma unroll
  for (int r = 0; r < R; ++r) { sr[r] = 0.0f; ss[r] = 0.0f; }

  // 4 chunks of 1024 j; lane-coalesced dwordx4 loads on the VMEM pipe.
  for (int k = 0; k < HALF; k += 1024) {
    const int j = jbase + k + tid * 4;
    float4 t4  = *(const float4*)(T  + j);
    float4 pr4 = *(const float4*)(Pr + j);
    float4 ps4 = *(const float4*)(Ps + j);
    int4   e4  = *(const int4*)(E  + j);
    float er0 = __expf(pr4.x), er1 = __expf(pr4.y),
          er2 = __expf(pr4.z), er3 = __expf(pr4.w);
    float es0 = e4.x ? __expf(ps4.x) : 0.0f;
    float es1 = e4.y ? __expf(ps4.y) : 0.0f;
    float es2 = e4.z ? __expf(ps4.z) : 0.0f;
    float es3 = e4.w ? __expf(ps4.w) : 0.0f;
#pragma unroll
    for (int r = 0; r < R; ++r) {
      bool g0 = t4.x > Ti[r];  sr[r] += g0 ? er0 : 0.0f;  ss[r] += g0 ? 0.0f : es0;
      bool g1 = t4.y > Ti[r];  sr[r] += g1 ? er1 : 0.0f;  ss[r] += g1 ? 0.0f : es1;
      bool g2 = t4.z > Ti[r];  sr[r] += g2 ? er2 : 0.0f;  ss[r] += g2 ? 0.0f : es2;
      bool g3 = t4.w > Ti[r];  sr[r] += g3 ? er3 : 0.0f;  ss[r] += g3 ? 0.0f : es3;
    }
  }

  // wave shuffle reduction, then cross-wave via LDS
#pragma unroll
  for (int r = 0; r < R; ++r) {
    for (int off = 32; off > 0; off >>= 1) {
      sr[r] += __shfl_down(sr[r], off);
      ss[r] += __shfl_down(ss[r], off);
    }
  }
  __shared__ float sh[4][2 * R];
  const int wid = tid >> 6, lane = tid & 63;
  if (lane == 0) {
#pragma unroll
    for (int r = 0; r < R; ++r) { sh[wid][r] = sr[r]; sh[wid][R + r] = ss[r]; }
  }
  __syncthreads();
  if (tid < 2 * R) {
    float v = sh[0][tid] + sh[1][tid] + sh[2][tid] + sh[3][tid];
    float* SR = h ? sumR1 : sumR0;
    float* SS = h ? sumS1 : sumS0;
    if (tid < R) SR[row0 + tid] = v;
    else         SS[row0 + (tid - R)] = v;   // complement sum incl. diagonal
  }
}

__global__ __launch_bounds__(1024) void ds_finalize(
    const float* __restrict__ Pr, const float* __restrict__ Ps,
    const int* __restrict__ E,
    const float* __restrict__ sumR0, const float* __restrict__ sumR1,
    const float* __restrict__ sumS0, const float* __restrict__ sumS1,
    float* __restrict__ out) {
  float nr = 0.0f, dr = 0.0f, ns = 0.0f, nds = 0.0f;
  for (int i = threadIdx.x; i < NN; i += 1024) {
    const int e = E[i];
    const float prv = Pr[i], psv = Ps[i];
    const float es_diag = e ? __expf(psv) : 0.0f;  // identical expr -> exact
    const float srv = sumR0[i] + sumR1[i];
    const float ssv = (sumS0[i] + sumS1[i]) - es_diag;  // remove diagonal
    const float wr  = (e != 0 && srv > 0.0f) ? 1.0f : 0.0f;
    const float wsv = (ssv > 0.0f) ? 1.0f : 0.0f;
    nr  += wr  * (prv - logf(srv + EPSF));
    dr  += wr;
    ns  += wsv * (psv - logf(ssv + EPSF));
    nds += wsv;
  }
  for (int off = 32; off > 0; off >>= 1) {
    nr  += __shfl_down(nr,  off);
    dr  += __shfl_down(dr,  off);
    ns  += __shfl_down(ns,  off);
    nds += __shfl_down(nds, off);
  }
  __shared__ float sh[4][16];
  const int wid = threadIdx.x >> 6, lane = threadIdx.x & 63;
  if (lane == 0) {
    sh[0][wid] = nr; sh[1][wid] = dr; sh[2][wid] = ns; sh[3][wid] = nds;
  }
  __syncthreads();
  if (threadIdx.x == 0) {
    float NR = 0, DR = 0, NS = 0, DS = 0;
#pragma unroll
    for (int w = 0; w < 16; ++w) {
      NR += sh[0][w]; DR += sh[1][w]; NS += sh[2][w]; DS += sh[3][w];
    }
    out[0] = -NR / DR;
    out[1] = -NS / DS;
  }
}

extern "C" void kernel_launch(void* const* d_in, const int* in_sizes, int n_in,
                              void* d_out, int out_size, void* d_ws, size_t ws_size,
                              hipStream_t stream) {
  const float* Pr = (const float*)d_in[0];
  const float* Ps = (const float*)d_in[1];
  const float* T  = (const float*)d_in[2];
  const int*   E  = (const int*)d_in[3];
  float* out = (float*)d_out;

  float* ws    = (float*)d_ws;
  float* sumR0 = ws;
  float* sumR1 = ws + NN;
  float* sumS0 = ws + 2 * NN;
  float* sumS1 = ws + 3 * NN;

  ds_main<<<GX, 256, 0, stream>>>(Pr, Ps, T, E, sumR0, sumR1, sumS0, sumS1);
  ds_finalize<<<1, 1024, 0, stream>>>(Pr, Ps, E, sumR0, sumR1, sumS0, sumS1, out);
}